// Round 1
// baseline (205.306 us; speedup 1.0000x reference)
//
#include <hip/hip_runtime.h>
#include <math.h>

#define B_    4
#define CIN_  64
#define COUT_ 64
#define N_    32768
#define S_    8192
#define K_    32
#define KS_   16

// ---------------------------------------------------------------------------
// Kernel A: transpose x [B][64][N] -> xT [B][N][64] so neighbor gathers of all
// 64 channels are contiguous 256B reads.
// ---------------------------------------------------------------------------
__global__ __launch_bounds__(256) void transpose_x_kernel(
    const float* __restrict__ x, float* __restrict__ xT)
{
    __shared__ float tile[64][65];
    const int b  = blockIdx.y;
    const int n0 = blockIdx.x * 64;
    const int tx = threadIdx.x & 63;
    const int ty = threadIdx.x >> 6;

    const float* xb = x + (size_t)b * CIN_ * N_;
    #pragma unroll
    for (int c = ty; c < 64; c += 4)
        tile[c][tx] = xb[(size_t)c * N_ + n0 + tx];
    __syncthreads();
    float* xTb = xT + ((size_t)b * N_ + n0) * 64;
    #pragma unroll
    for (int nn = ty; nn < 64; nn += 4)
        xTb[(size_t)nn * 64 + tx] = tile[tx][nn];
}

// ---------------------------------------------------------------------------
// Kernel B: per support point, run the fc1/fc2/fc3 + maxpool pipeline (one
// 32-lane group per point, lane = neighbor), then compute
// feats[c][k] = sum_n x_g[c][n] * mat3[k][n] (lane = channel) and write
// feats[b][s][c*16+k] to workspace.
// ---------------------------------------------------------------------------
__global__ __launch_bounds__(256) void fka_feats_kernel(
    const float* __restrict__ pos, const float* __restrict__ sup,
    const int*   __restrict__ nbr, const float* __restrict__ radius,
    const float* __restrict__ w1,  const float* __restrict__ w2,
    const float* __restrict__ w3,  const float* __restrict__ xT,
    float* __restrict__ feats, int s_base, int S_chunk)
{
    __shared__ float m3s[8][32][16];   // [local point][n][k]
    __shared__ int   idxs[8][32];

    const int b  = blockIdx.y;
    const int t  = threadIdx.x;
    const int g  = t >> 5;             // point group 0..7
    const int n  = t & 31;             // neighbor lane
    const int sl = blockIdx.x * 8 + g; // local s within chunk
    const int s  = s_base + sl;        // global s

    // ---- phase 1: fc pipeline, lane n handles neighbor n of point s ----
    const int raw  = nbr[(((size_t)b * S_ + s) << 5) + n];
    const bool valid = raw > -1;
    const int id   = valid ? raw : 0;

    unsigned long long bal = __ballot(valid);
    unsigned bits = (unsigned)(bal >> (t & 32));     // my 32-lane half
    const float nrm = sqrtf((float)__popc(bits));
    float dw = valid ? (1.0f / fmaxf(nrm, 1e-12f)) : 0.0f;

    float px = pos[(size_t)(b * 3 + 0) * N_ + id] - sup[(size_t)(b * 3 + 0) * S_ + s];
    float py = pos[(size_t)(b * 3 + 1) * N_ + id] - sup[(size_t)(b * 3 + 1) * S_ + s];
    float pz = pos[(size_t)(b * 3 + 2) * N_ + id] - sup[(size_t)(b * 3 + 2) * S_ + s];
    if (isinf(px)) dw = 0.0f;                         // mask_pts factor
    px = (isnan(px) || isinf(px)) ? 0.0f : px;        // nan_to_num
    py = (isnan(py) || isinf(py)) ? 0.0f : py;
    pz = (isnan(pz) || isinf(pz)) ? 0.0f : pz;
    const float inv_r = 1.0f / radius[0];
    px *= inv_r; py *= inv_r; pz *= inv_r;

    float m1[16], mp1[16], m2[16], mp2[16], m3[16];

    #pragma unroll
    for (int k = 0; k < 16; ++k) {
        float v = w1[k * 3 + 0] * px + w1[k * 3 + 1] * py + w1[k * 3 + 2] * pz;
        m1[k] = fmaxf(v, 0.0f) * dw;
    }
    #pragma unroll
    for (int k = 0; k < 16; ++k) {
        float v = m1[k];
        #pragma unroll
        for (int off = 16; off; off >>= 1)
            v = fmaxf(v, __shfl_xor(v, off, 32));
        mp1[k] = v;
    }
    #pragma unroll
    for (int k = 0; k < 16; ++k) {
        const float* wr = &w2[k * 32];
        float v = 0.0f;
        #pragma unroll
        for (int j = 0; j < 16; ++j) v = fmaf(wr[j], m1[j], v);
        #pragma unroll
        for (int j = 0; j < 16; ++j) v = fmaf(wr[16 + j], mp1[j], v);
        m2[k] = fmaxf(v, 0.0f) * dw;
    }
    #pragma unroll
    for (int k = 0; k < 16; ++k) {
        float v = m2[k];
        #pragma unroll
        for (int off = 16; off; off >>= 1)
            v = fmaxf(v, __shfl_xor(v, off, 32));
        mp2[k] = v;
    }
    #pragma unroll
    for (int k = 0; k < 16; ++k) {
        const float* wr = &w3[k * 32];
        float v = 0.0f;
        #pragma unroll
        for (int j = 0; j < 16; ++j) v = fmaf(wr[j], m2[j], v);
        #pragma unroll
        for (int j = 0; j < 16; ++j) v = fmaf(wr[16 + j], mp2[j], v);
        m3[k] = fmaxf(v, 0.0f) * dw;
    }

    idxs[g][n] = id;
    #pragma unroll
    for (int k = 0; k < 16; ++k) m3s[g][n][k] = m3[k];
    __syncthreads();

    // ---- phase 2: feats. wave w handles points 2w, 2w+1; lane = channel ----
    const int wv = t >> 6;
    const int c  = t & 63;
    const size_t xTb = (size_t)b * N_ * 64;

    for (int pp = 0; pp < 2; ++pp) {
        const int p = wv * 2 + pp;
        float f[16];
        #pragma unroll
        for (int k = 0; k < 16; ++k) f[k] = 0.0f;

        const int* ids = idxs[p];
        #pragma unroll 4
        for (int nn = 0; nn < 32; ++nn) {
            const float xv = xT[xTb + ((size_t)ids[nn] << 6) + c];
            const float* mm = m3s[p][nn];
            #pragma unroll
            for (int k = 0; k < 16; ++k) f[k] = fmaf(xv, mm[k], f[k]);
        }

        float* fb = feats + (((size_t)b * S_chunk + (size_t)blockIdx.x * 8 + p) << 10) + (c << 4);
        #pragma unroll
        for (int q = 0; q < 4; ++q)
            *(float4*)(fb + q * 4) = make_float4(f[q*4], f[q*4+1], f[q*4+2], f[q*4+3]);
    }
}

// ---------------------------------------------------------------------------
// Kernel C: out[b][o][s] = sum_ck wcv[o][ck] * feats[b][s][ck]  (K = 1024)
// Tiled f32 GEMM: 64 o x 64 s per block, 4x4 register tile per lane.
// ---------------------------------------------------------------------------
__global__ __launch_bounds__(256) void fka_out_kernel(
    const float* __restrict__ wcv,   // [64][1024]
    const float* __restrict__ feats, // [B][S_chunk][1024]
    const float* __restrict__ sup,   // [B][3][S]
    float* __restrict__ out,         // [B][64][S]
    int s_base, int S_chunk)
{
    __shared__ float wS[64][65];
    __shared__ float fS[64][65];

    const int b   = blockIdx.y;
    const int t   = threadIdx.x;
    const int sl0 = blockIdx.x * 64;      // local s-tile base within chunk
    const int tx  = t & 15;               // s sub-group
    const int o0  = (t >> 4) * 4;         // 4 o rows per lane
    const int sl4 = tx * 4;               // 4 s cols per lane

    const float* fbase = feats + ((size_t)b * S_chunk + sl0) * 1024;

    float acc[4][4];
    #pragma unroll
    for (int i = 0; i < 4; ++i)
        #pragma unroll
        for (int j = 0; j < 4; ++j) acc[i][j] = 0.0f;

    const int kq = tx * 4;
    const int r0 = t >> 4;

    for (int k0 = 0; k0 < 1024; k0 += 64) {
        #pragma unroll
        for (int rr = 0; rr < 4; ++rr) {
            const int row = r0 + rr * 16;
            const float4 wv4 = *(const float4*)&wcv[(size_t)row * 1024 + k0 + kq];
            const float4 fv4 = *(const float4*)&fbase[(size_t)row * 1024 + k0 + kq];
            wS[row][kq]     = wv4.x; wS[row][kq + 1] = wv4.y;
            wS[row][kq + 2] = wv4.z; wS[row][kq + 3] = wv4.w;
            fS[row][kq]     = fv4.x; fS[row][kq + 1] = fv4.y;
            fS[row][kq + 2] = fv4.z; fS[row][kq + 3] = fv4.w;
        }
        __syncthreads();

        #pragma unroll 8
        for (int kk = 0; kk < 64; ++kk) {
            float wr[4], fr[4];
            #pragma unroll
            for (int i = 0; i < 4; ++i) wr[i] = wS[o0 + i][kk];
            #pragma unroll
            for (int j = 0; j < 4; ++j) fr[j] = fS[sl4 + j][kk];
            #pragma unroll
            for (int i = 0; i < 4; ++i)
                #pragma unroll
                for (int j = 0; j < 4; ++j)
                    acc[i][j] = fmaf(wr[i], fr[j], acc[i][j]);
        }
        __syncthreads();
    }

    #pragma unroll
    for (int j = 0; j < 4; ++j) {
        const int s = s_base + sl0 + sl4 + j;
        const bool inf_s = isinf(sup[(size_t)b * 3 * S_ + s]);   // sup[b][0][s]
        #pragma unroll
        for (int i = 0; i < 4; ++i) {
            const float v = inf_s ? INFINITY : acc[i][j];
            out[((size_t)(b * COUT_) + o0 + i) * S_ + s] = v;
        }
    }
}

// ---------------------------------------------------------------------------
extern "C" void kernel_launch(void* const* d_in, const int* in_sizes, int n_in,
                              void* d_out, int out_size, void* d_ws, size_t ws_size,
                              hipStream_t stream)
{
    const float* x   = (const float*)d_in[0];
    const float* pos = (const float*)d_in[1];
    const float* sup = (const float*)d_in[2];
    const int*   nbr = (const int*)d_in[3];
    const float* rad = (const float*)d_in[4];
    const float* w1  = (const float*)d_in[5];
    const float* w2  = (const float*)d_in[6];
    const float* w3  = (const float*)d_in[7];
    const float* wcv = (const float*)d_in[8];
    float* out = (float*)d_out;

    float* xT = (float*)d_ws;
    const size_t xT_bytes = (size_t)B_ * N_ * CIN_ * sizeof(float);
    float* feats = (float*)((char*)d_ws + xT_bytes);
    const size_t avail = (ws_size > xT_bytes) ? (ws_size - xT_bytes) : 0;

    // largest s-chunk whose feats buffer [B][S_chunk][1024] f32 fits in ws
    int S_chunk = S_;
    while (S_chunk > 64 && (size_t)B_ * (size_t)S_chunk * 1024 * sizeof(float) > avail)
        S_chunk >>= 1;

    transpose_x_kernel<<<dim3(N_ / 64, B_), 256, 0, stream>>>(x, xT);

    for (int sb = 0; sb < S_; sb += S_chunk) {
        fka_feats_kernel<<<dim3(S_chunk / 8, B_), 256, 0, stream>>>(
            pos, sup, nbr, rad, w1, w2, w3, xT, feats, sb, S_chunk);
        fka_out_kernel<<<dim3(S_chunk / 64, B_), 256, 0, stream>>>(
            wcv, feats, sup, out, sb, S_chunk);
    }
}

// Round 2
// 133.480 us; speedup vs baseline: 1.5381x; 1.5381x over previous
//
#include <hip/hip_runtime.h>
#include <math.h>

#define B_    4
#define CIN_  64
#define COUT_ 64
#define N_    32768
#define S_    8192

typedef __attribute__((ext_vector_type(8))) short short8;
typedef __attribute__((ext_vector_type(8))) unsigned short ushort8;
typedef __attribute__((ext_vector_type(4))) unsigned short ushort4v;
typedef __attribute__((ext_vector_type(4))) float f32x4;

static __device__ __forceinline__ unsigned short f2bf(float x) {
    unsigned u = __float_as_uint(x);
    u += 0x7fffu + ((u >> 16) & 1u);
    return (unsigned short)(u >> 16);
}

// ---------------------------------------------------------------------------
// Kernel A1: transpose x [B][64][N] -> xT [B][N][64] (coalesced 256B gathers)
// ---------------------------------------------------------------------------
__global__ __launch_bounds__(256) void transpose_x_kernel(
    const float* __restrict__ x, float* __restrict__ xT)
{
    __shared__ float tile[64][65];
    const int b  = blockIdx.y;
    const int n0 = blockIdx.x * 64;
    const int tx = threadIdx.x & 63;
    const int ty = threadIdx.x >> 6;

    const float* xb = x + (size_t)b * CIN_ * N_;
    #pragma unroll
    for (int c = ty; c < 64; c += 4)
        tile[c][tx] = xb[(size_t)c * N_ + n0 + tx];
    __syncthreads();
    float* xTb = xT + ((size_t)b * N_ + n0) * 64;
    #pragma unroll
    for (int nn = ty; nn < 64; nn += 4)
        xTb[(size_t)nn * 64 + tx] = tile[tx][nn];
}

// ---------------------------------------------------------------------------
// Kernel A2: pos [B][3][N] -> posT [B][N][4] (one float4 gather per neighbor)
// ---------------------------------------------------------------------------
__global__ __launch_bounds__(256) void post_kernel(
    const float* __restrict__ pos, float* __restrict__ posT)
{
    const int b = blockIdx.y;
    const int n = blockIdx.x * 256 + threadIdx.x;
    const float* pb = pos + (size_t)b * 3 * N_;
    float4 v = make_float4(pb[n], pb[N_ + n], pb[2 * N_ + n], 0.0f);
    *(float4*)&posT[((size_t)b * N_ + n) * 4] = v;
}

// ---------------------------------------------------------------------------
// Kernel A3: wcv f32 [64][1024] -> bf16 (row-major, j = c*16+k)
// ---------------------------------------------------------------------------
__global__ __launch_bounds__(256) void wcvb_kernel(
    const float* __restrict__ wcv, unsigned short* __restrict__ wcvB)
{
    const int i = (blockIdx.x * 256 + threadIdx.x) * 4;
    float4 v = *(const float4*)&wcv[i];
    ushort4v o;
    o[0] = f2bf(v.x); o[1] = f2bf(v.y); o[2] = f2bf(v.z); o[3] = f2bf(v.w);
    *(ushort4v*)&wcvB[i] = o;
}

// ---------------------------------------------------------------------------
// Kernel B: per support point fc1/fc2/fc3 + maxpool pipeline, then
// feats[c][k] = sum_n x_g[c][n] * mat3[k][n], written as bf16 [s][c*16+k].
// ---------------------------------------------------------------------------
__global__ __launch_bounds__(256) void fka_feats_kernel(
    const float* __restrict__ posT, const float* __restrict__ sup,
    const int*   __restrict__ nbr, const float* __restrict__ radius,
    const float* __restrict__ w1,  const float* __restrict__ w2,
    const float* __restrict__ w3,  const float* __restrict__ xT,
    unsigned short* __restrict__ featsB, int s_base, int S_chunk)
{
    __shared__ float m3s[8][32][20];   // [point][n][k(+pad)] : pad 20 -> aligned float4, spread banks
    __shared__ int   idxs[8][32];

    const int b  = blockIdx.y;
    const int t  = threadIdx.x;
    const int g  = t >> 5;
    const int n  = t & 31;
    const int sl = blockIdx.x * 8 + g;
    const int s  = s_base + sl;

    // ---- phase 1: fc pipeline (lane = neighbor) ----
    const int raw   = nbr[(((size_t)b * S_ + s) << 5) + n];
    const bool valid = raw > -1;
    const int id    = valid ? raw : 0;

    unsigned long long bal = __ballot(valid);
    unsigned bits = (unsigned)(bal >> (t & 32));
    const float nrm = sqrtf((float)__popc(bits));
    float dw = valid ? (1.0f / fmaxf(nrm, 1e-12f)) : 0.0f;

    const float4 pg = *(const float4*)&posT[((size_t)b * N_ + id) * 4];
    float px = pg.x - sup[(size_t)(b * 3 + 0) * S_ + s];
    float py = pg.y - sup[(size_t)(b * 3 + 1) * S_ + s];
    float pz = pg.z - sup[(size_t)(b * 3 + 2) * S_ + s];
    if (isinf(px)) dw = 0.0f;
    px = (isnan(px) || isinf(px)) ? 0.0f : px;
    py = (isnan(py) || isinf(py)) ? 0.0f : py;
    pz = (isnan(pz) || isinf(pz)) ? 0.0f : pz;
    const float inv_r = 1.0f / radius[0];
    px *= inv_r; py *= inv_r; pz *= inv_r;

    float m1[16], mp1[16], m2[16], mp2[16], m3[16];

    #pragma unroll
    for (int k = 0; k < 16; ++k) {
        float v = w1[k * 3 + 0] * px + w1[k * 3 + 1] * py + w1[k * 3 + 2] * pz;
        m1[k] = fmaxf(v, 0.0f) * dw;
    }
    #pragma unroll
    for (int k = 0; k < 16; ++k) {
        float v = m1[k];
        #pragma unroll
        for (int off = 16; off; off >>= 1)
            v = fmaxf(v, __shfl_xor(v, off, 32));
        mp1[k] = v;
    }
    #pragma unroll
    for (int k = 0; k < 16; ++k) {
        const float* wr = &w2[k * 32];
        float v = 0.0f;
        #pragma unroll
        for (int j = 0; j < 16; ++j) v = fmaf(wr[j], m1[j], v);
        #pragma unroll
        for (int j = 0; j < 16; ++j) v = fmaf(wr[16 + j], mp1[j], v);
        m2[k] = fmaxf(v, 0.0f) * dw;
    }
    #pragma unroll
    for (int k = 0; k < 16; ++k) {
        float v = m2[k];
        #pragma unroll
        for (int off = 16; off; off >>= 1)
            v = fmaxf(v, __shfl_xor(v, off, 32));
        mp2[k] = v;
    }
    #pragma unroll
    for (int k = 0; k < 16; ++k) {
        const float* wr = &w3[k * 32];
        float v = 0.0f;
        #pragma unroll
        for (int j = 0; j < 16; ++j) v = fmaf(wr[j], m2[j], v);
        #pragma unroll
        for (int j = 0; j < 16; ++j) v = fmaf(wr[16 + j], mp2[j], v);
        m3[k] = fmaxf(v, 0.0f) * dw;
    }

    idxs[g][n] = id;
    float* mrow = &m3s[g][n][0];
    *(float4*)(mrow +  0) = make_float4(m3[0],  m3[1],  m3[2],  m3[3]);
    *(float4*)(mrow +  4) = make_float4(m3[4],  m3[5],  m3[6],  m3[7]);
    *(float4*)(mrow +  8) = make_float4(m3[8],  m3[9],  m3[10], m3[11]);
    *(float4*)(mrow + 12) = make_float4(m3[12], m3[13], m3[14], m3[15]);
    __syncthreads();

    // ---- phase 2: feats (lane = channel), 2 points per wave ----
    const int wv = t >> 6;
    const int c  = t & 63;
    const size_t xTb = (size_t)b * N_ * 64;

    for (int pp = 0; pp < 2; ++pp) {
        const int p = wv * 2 + pp;
        const int* ids = idxs[p];
        float f[16];
        #pragma unroll
        for (int k = 0; k < 16; ++k) f[k] = 0.0f;

        #pragma unroll 4
        for (int nn = 0; nn < 32; ++nn) {
            const float xv = xT[xTb + ((size_t)ids[nn] << 6) + c];
            const float4 ma = *(const float4*)&m3s[p][nn][0];
            const float4 mb = *(const float4*)&m3s[p][nn][4];
            const float4 mc = *(const float4*)&m3s[p][nn][8];
            const float4 md = *(const float4*)&m3s[p][nn][12];
            f[0]  = fmaf(xv, ma.x, f[0]);  f[1]  = fmaf(xv, ma.y, f[1]);
            f[2]  = fmaf(xv, ma.z, f[2]);  f[3]  = fmaf(xv, ma.w, f[3]);
            f[4]  = fmaf(xv, mb.x, f[4]);  f[5]  = fmaf(xv, mb.y, f[5]);
            f[6]  = fmaf(xv, mb.z, f[6]);  f[7]  = fmaf(xv, mb.w, f[7]);
            f[8]  = fmaf(xv, mc.x, f[8]);  f[9]  = fmaf(xv, mc.y, f[9]);
            f[10] = fmaf(xv, mc.z, f[10]); f[11] = fmaf(xv, mc.w, f[11]);
            f[12] = fmaf(xv, md.x, f[12]); f[13] = fmaf(xv, md.y, f[13]);
            f[14] = fmaf(xv, md.z, f[14]); f[15] = fmaf(xv, md.w, f[15]);
        }

        ushort8 lo, hi;
        #pragma unroll
        for (int q = 0; q < 8; ++q) { lo[q] = f2bf(f[q]); hi[q] = f2bf(f[8 + q]); }
        unsigned short* fb = featsB
            + (((size_t)b * S_chunk + (size_t)blockIdx.x * 8 + p) << 10) + (c << 4);
        *(ushort8*)(fb)     = lo;
        *(ushort8*)(fb + 8) = hi;
    }
}

// ---------------------------------------------------------------------------
// Kernel C: out[b][64][s] = wcvB[64][1024] x featsB[s][1024]^T via bf16 MFMA.
// 512 threads = 8 waves; block tile 64o x 128s; wave tile 32o x 32s.
// ---------------------------------------------------------------------------
__global__ __launch_bounds__(512) void fka_out_mfma(
    const unsigned short* __restrict__ wcvB,
    const unsigned short* __restrict__ featsB,
    const float* __restrict__ sup,
    float* __restrict__ out, int s_base, int S_chunk)
{
    const int b    = blockIdx.y;
    const int t    = threadIdx.x;
    const int wv   = t >> 6;
    const int wv_o = wv & 1;          // o-half (32)
    const int wv_s = wv >> 1;         // s-quarter (32)
    const int l    = t & 63;
    const int l15  = l & 15;
    const int lq   = l >> 4;
    const int kq   = lq * 8;

    const unsigned short* ap = wcvB + (size_t)(wv_o * 32 + l15) * 1024 + kq;
    const unsigned short* bp = featsB
        + ((size_t)b * S_chunk + (size_t)blockIdx.x * 128 + wv_s * 32 + l15) * 1024 + kq;

    f32x4 acc[2][2];
    #pragma unroll
    for (int i = 0; i < 2; ++i)
        #pragma unroll
        for (int j = 0; j < 2; ++j) acc[i][j] = (f32x4){0.f, 0.f, 0.f, 0.f};

    #pragma unroll 4
    for (int ks = 0; ks < 32; ++ks) {
        const int k0 = ks * 32;
        short8 a0 = *(const short8*)(ap + k0);
        short8 a1 = *(const short8*)(ap + 16 * 1024 + k0);
        short8 b0 = *(const short8*)(bp + k0);
        short8 b1 = *(const short8*)(bp + 16 * 1024 + k0);
        acc[0][0] = __builtin_amdgcn_mfma_f32_16x16x32_bf16(a0, b0, acc[0][0], 0, 0, 0);
        acc[0][1] = __builtin_amdgcn_mfma_f32_16x16x32_bf16(a0, b1, acc[0][1], 0, 0, 0);
        acc[1][0] = __builtin_amdgcn_mfma_f32_16x16x32_bf16(a1, b0, acc[1][0], 0, 0, 0);
        acc[1][1] = __builtin_amdgcn_mfma_f32_16x16x32_bf16(a1, b1, acc[1][1], 0, 0, 0);
    }

    #pragma unroll
    for (int sc = 0; sc < 2; ++sc) {
        const int s = s_base + blockIdx.x * 128 + wv_s * 32 + sc * 16 + l15;
        const bool infs = isinf(sup[(size_t)b * 3 * S_ + s]);
        #pragma unroll
        for (int oc = 0; oc < 2; ++oc)
            #pragma unroll
            for (int r = 0; r < 4; ++r) {
                const int o = wv_o * 32 + oc * 16 + lq * 4 + r;
                out[((size_t)b * COUT_ + o) * S_ + s] = infs ? INFINITY : acc[oc][sc][r];
            }
    }
}

// ---------------------------------------------------------------------------
extern "C" void kernel_launch(void* const* d_in, const int* in_sizes, int n_in,
                              void* d_out, int out_size, void* d_ws, size_t ws_size,
                              hipStream_t stream)
{
    const float* x   = (const float*)d_in[0];
    const float* pos = (const float*)d_in[1];
    const float* sup = (const float*)d_in[2];
    const int*   nbr = (const int*)d_in[3];
    const float* rad = (const float*)d_in[4];
    const float* w1  = (const float*)d_in[5];
    const float* w2  = (const float*)d_in[6];
    const float* w3  = (const float*)d_in[7];
    const float* wcv = (const float*)d_in[8];
    float* out = (float*)d_out;

    char* p = (char*)d_ws;
    float* xT = (float*)p;                 p += (size_t)B_ * N_ * 64 * sizeof(float);
    float* posT = (float*)p;               p += (size_t)B_ * N_ * 4 * sizeof(float);
    unsigned short* wcvB = (unsigned short*)p; p += (size_t)COUT_ * 1024 * sizeof(unsigned short);
    unsigned short* featsB = (unsigned short*)p;
    const size_t used = (size_t)(p - (char*)d_ws);
    const size_t avail = (ws_size > used) ? (ws_size - used) : 0;

    int S_chunk = S_;
    while (S_chunk > 128 && (size_t)B_ * (size_t)S_chunk * 1024 * 2 > avail)
        S_chunk >>= 1;

    transpose_x_kernel<<<dim3(N_ / 64, B_), 256, 0, stream>>>(x, xT);
    post_kernel<<<dim3(N_ / 256, B_), 256, 0, stream>>>(pos, posT);
    wcvb_kernel<<<dim3(64), 256, 0, stream>>>(wcv, wcvB);

    for (int sb = 0; sb < S_; sb += S_chunk) {
        fka_feats_kernel<<<dim3(S_chunk / 8, B_), 256, 0, stream>>>(
            posT, sup, nbr, rad, w1, w2, w3, xT, featsB, sb, S_chunk);
        fka_out_mfma<<<dim3(S_chunk / 128, B_), 512, 0, stream>>>(
            wcvB, featsB, sup, out, sb, S_chunk);
    }
}